// Round 8
// baseline (163.028 us; speedup 1.0000x reference)
//
#include <hip/hip_runtime.h>

#define ALPHA1 1.2566f
#define ALPHA2 1.5f
#define ALPHA3 0.9f
#define S_STAR 20.0f
#define TAU    4.0f

constexpr int TPB = 256;
constexpr int JPT = 2;             // j's per thread
constexpr int JPB = TPB * JPT;     // 512 j's per block
constexpr unsigned MAGIC = 0x5CA1AB1Eu;

typedef float f32x4 __attribute__((ext_vector_type(4)));
typedef float f32x2 __attribute__((ext_vector_type(2)));

struct FoldLds {
    float T[100][8];    // W2 @ [W1|b1] (+b2 in col 6)
    float W3s[400];
    float b3s[4];
};

// Per-block fold of the purely-linear MLP into McS[4][8] ([m][6]=c[m]).
// Two internal barriers; ~2 us cold. Used by block 0 (publisher) and as a
// scheduling-independent fallback by any block whose flag poll times out.
__device__ __forceinline__ void do_fold(
        FoldLds& L, float* McS, int tid,
        const float* __restrict__ W1, const float* __restrict__ b1,
        const float* __restrict__ W2, const float* __restrict__ b2,
        const float* __restrict__ W3, const float* __restrict__ b3) {
    if (tid >= 128 && tid < 228) {
        const int i = tid - 128;
        *(f32x4*)(&L.W3s[i * 4]) = *(const f32x4*)(W3 + i * 4);
    } else if (tid >= 228 && tid < 232) {
        L.b3s[tid - 228] = b3[tid - 228];
    }
    if (tid < 100) {
        float acc[7] = {0.f, 0.f, 0.f, 0.f, 0.f, 0.f, 0.f};
        acc[6] = b2[tid];
        const float2* wrow = (const float2*)(W2 + tid * 50);
        #pragma unroll 5
        for (int hh = 0; hh < 25; ++hh) {
            const float2 w = wrow[hh];
            const int h = 2 * hh;
            // W1/b1 indices thread-uniform -> s_load broadcasts
            #pragma unroll
            for (int k = 0; k < 6; ++k)
                acc[k] = fmaf(w.y, W1[(h + 1) * 6 + k],
                          fmaf(w.x, W1[h * 6 + k], acc[k]));
            acc[6] = fmaf(w.y, b1[h + 1], fmaf(w.x, b1[h], acc[6]));
        }
        #pragma unroll
        for (int k = 0; k < 7; ++k) L.T[tid][k] = acc[k];
    }
    __syncthreads();
    if (tid < 28) {
        const int m = tid / 7, k = tid % 7;
        float s = (k == 6) ? L.b3s[m] : 0.f;
        #pragma unroll 10
        for (int i = 0; i < 100; ++i)
            s = fmaf(L.W3s[m * 100 + i], L.T[i][k], s);
        McS[m * 8 + k] = s;
    }
    if (tid >= 28 && tid < 32) McS[(tid - 28) * 8 + 7] = 0.f;
    __syncthreads();
}

__global__ __launch_bounds__(TPB, 8) void fused_kernel(
        const float* __restrict__ z,
        const float* __restrict__ W1, const float* __restrict__ b1,
        const float* __restrict__ W2, const float* __restrict__ b2,
        const float* __restrict__ W3, const float* __restrict__ b3,
        float* __restrict__ ws, float* __restrict__ out, long long B) {
    __shared__ FoldLds L;
    __shared__ float McS[32];
    __shared__ int tmo;

    const int tid = threadIdx.x;
    const long long j0 = ((long long)blockIdx.x * TPB + tid) * JPT;

    // ---- z streaming loads first; they drain (vmcnt) at the first barrier,
    //      so HBM latency overlaps the fold / flag wait ----
    const f32x2 c1 = *(const f32x2*)(z + 1 * B + j0);
    const f32x2 c2 = *(const f32x2*)(z + 2 * B + j0);
    const f32x2 c3 = *(const f32x2*)(z + 3 * B + j0);
    const f32x2 c4 = *(const f32x2*)(z + 4 * B + j0);
    const f32x2 c5 = *(const f32x2*)(z + 5 * B + j0);
    const f32x4 r0 = *(const f32x4*)(z + j0 * 6);
    const f32x4 r1 = *(const f32x4*)(z + j0 * 6 + 4);
    const f32x4 r2 = *(const f32x4*)(z + j0 * 6 + 8);

    unsigned* flag = (unsigned*)(ws + 64);   // own cache line (byte 256)

    if (blockIdx.x == 0) {
        // ---- publisher: fold -> LDS -> ws, then release flag ----
        do_fold(L, McS, tid, W1, b1, W2, b2, W3, b3);
        if (tid < 32) ws[tid] = McS[tid];
        __syncthreads();                     // ws stores in L2 before release
        if (tid == 0)
            __hip_atomic_store(flag, MAGIC, __ATOMIC_RELEASE,
                               __HIP_MEMORY_SCOPE_AGENT);
    } else {
        if (tid == 0) {
            int ok = 0;
            for (int it = 0; it < 256; ++it) {   // ~0.85us per poll
                if (__hip_atomic_load(flag, __ATOMIC_ACQUIRE,
                                      __HIP_MEMORY_SCOPE_AGENT) == MAGIC) {
                    ok = 1; break;
                }
                __builtin_amdgcn_s_sleep(32);
            }
            tmo = 1 - ok;
        }
        __syncthreads();
        if (tmo == 0) {
            if (tid < 32) {
                const unsigned bits = __hip_atomic_load(
                    (const unsigned*)ws + tid, __ATOMIC_RELAXED,
                    __HIP_MEMORY_SCOPE_AGENT);
                McS[tid] = __uint_as_float(bits);
            }
            __syncthreads();
        } else {
            // scheduling-independent fallback: fold locally
            do_fold(L, McS, tid, W1, b1, W2, b2, W3, b3);
        }
    }

    // ---- math phase (Mc via LDS broadcast) ----
    const float g1 = TAU * ALPHA3;
    const float g2 = TAU * ALPHA1;
    const float g3 = 1.f - TAU * ALPHA2 - TAU * ALPHA3;
    const float g4 = -TAU * ALPHA1;
    const float g5 = TAU * ALPHA2 - 1.f;
    const float invA1 = -0.25f;                 // 1/(-TAU), exact
    const float invA2 = -1.f / (TAU * ALPHA3);

    const float zz[12] = {r0.x, r0.y, r0.z, r0.w,
                          r1.x, r1.y, r1.z, r1.w,
                          r2.x, r2.y, r2.z, r2.w};

    f32x2 o;
    #pragma unroll
    for (int r = 0; r < 2; ++r) {
        float u[4];
        #pragma unroll
        for (int m = 0; m < 4; ++m) {
            float s = McS[m * 8 + 6];
            #pragma unroll
            for (int k = 0; k < 6; ++k)
                s = fmaf(McS[m * 8 + k], zz[r * 6 + k], s);
            u[m] = s;
        }
        const float x1 = r ? c1.y : c1.x;
        const float x2 = r ? c2.y : c2.x;
        const float x3 = r ? c3.y : c3.x;
        const float x4 = r ? c4.y : c4.x;
        const float x5 = r ? c5.y : c5.x;

        const float fx2 = x1 - x3;
        const float fx3 = ALPHA3 * x1 + ALPHA1 * x2 - ALPHA2 * x3;
        const float fx4 = x3 - x5;
        const float fx5 = ALPHA3 * x3 + ALPHA1 * x4 - ALPHA2 * x5;

        const float eta1 = x2 + S_STAR - TAU * (x3 - x1);
        const float bb1  = (fx2 - TAU * fx3) + u[1] * eta1;

        const float eta2a = x4 + S_STAR - TAU * (x5 - x3);
        const float eta2b = g1 * x1 + g2 * x2 + g3 * x3 + g4 * x4 + g5 * x5;
        const float d3ufX = g2 * fx2 + g3 * fx3 + g4 * fx4 + g5 * fx5;
        const float bb2   = d3ufX + u[2] * eta2a + u[3] * eta2b;

        const float lb = fmaxf(bb1 * invA1, bb2 * invA2);
        const float xu = 2.f * u[0];
        o[r] = fminf(fmaxf(xu, lb), 1e30f);
    }
    *(f32x2*)(out + j0) = o;
}

extern "C" void kernel_launch(void* const* d_in, const int* in_sizes, int n_in,
                              void* d_out, int out_size, void* d_ws, size_t ws_size,
                              hipStream_t stream) {
    const float* z  = (const float*)d_in[0];
    // d_in[1] = tilde_vh (unused by the reference output)
    const float* W1 = (const float*)d_in[2];
    const float* b1 = (const float*)d_in[3];
    const float* W2 = (const float*)d_in[4];
    const float* b2 = (const float*)d_in[5];
    const float* W3 = (const float*)d_in[6];
    const float* b3 = (const float*)d_in[7];
    float* out = (float*)d_out;
    float* ws  = (float*)d_ws;

    const long long B = (long long)in_sizes[0] / 6;   // 1048576
    const int blocks = (int)(B / JPB);                // 2048

    fused_kernel<<<blocks, TPB, 0, stream>>>(z, W1, b1, W2, b2, W3, b3,
                                             ws, out, B);
}

// Round 10
// 97.208 us; speedup vs baseline: 1.6771x; 1.6771x over previous
//
#include <hip/hip_runtime.h>

#define ALPHA1 1.2566f
#define ALPHA2 1.5f
#define ALPHA3 0.9f
#define S_STAR 20.0f
#define TAU    4.0f

constexpr int TPB = 256;
constexpr int JPT = 4;             // j's per thread
constexpr int JPB = TPB * JPT;     // 1024 j's per block

typedef float f32x4 __attribute__((ext_vector_type(4)));

// ---------------------------------------------------------------------------
// Setup (1 block): fold the purely-linear MLP into Mc[4][8] in d_ws.
// Split-launch publication: the kernel boundary's cache flush makes ws
// visible to all XCDs (device-scope flags through dirty-poisoned ws lines
// are NOT reliable -- measured round 8).
// ---------------------------------------------------------------------------
__global__ __launch_bounds__(TPB) void setup_kernel(
        const float* __restrict__ W1, const float* __restrict__ b1,
        const float* __restrict__ W2, const float* __restrict__ b2,
        const float* __restrict__ W3, const float* __restrict__ b3,
        float* __restrict__ ws) {
    __shared__ float T[100][8];
    __shared__ float W3s[400];
    __shared__ float b3s[4];
    const int tid = threadIdx.x;

    if (tid >= 128 && tid < 228) {
        const int i = tid - 128;
        *(f32x4*)(&W3s[i * 4]) = *(const f32x4*)(W3 + i * 4);
    } else if (tid >= 228 && tid < 232) {
        b3s[tid - 228] = b3[tid - 228];
    }

    if (tid < 100) {
        float acc[7] = {0.f, 0.f, 0.f, 0.f, 0.f, 0.f, 0.f};
        acc[6] = b2[tid];
        const float2* wrow = (const float2*)(W2 + tid * 50);
        #pragma unroll 5
        for (int hh = 0; hh < 25; ++hh) {
            const float2 w = wrow[hh];
            const int h = 2 * hh;
            // W1/b1 indices thread-uniform -> s_load broadcasts
            #pragma unroll
            for (int k = 0; k < 6; ++k)
                acc[k] = fmaf(w.y, W1[(h + 1) * 6 + k],
                          fmaf(w.x, W1[h * 6 + k], acc[k]));
            acc[6] = fmaf(w.y, b1[h + 1], fmaf(w.x, b1[h], acc[6]));
        }
        #pragma unroll
        for (int k = 0; k < 7; ++k) T[tid][k] = acc[k];
    }
    __syncthreads();

    if (tid < 28) {
        const int m = tid / 7, k = tid % 7;
        float s = (k == 6) ? b3s[m] : 0.f;
        #pragma unroll 10
        for (int i = 0; i < 100; ++i)
            s = fmaf(W3s[m * 100 + i], T[i][k], s);
        ws[m * 8 + k] = s;
    }
    if (tid >= 28 && tid < 32) ws[(tid - 28) * 8 + 7] = 0.f;
}

// ---------------------------------------------------------------------------
// Main: barrier-free, LDS-free streaming, 4 j's per thread, all float4
// transactions (row: 6, col: 5, out: 1). Mc via uniform-address s_load
// broadcasts (L2-hot after the first wave).
// ---------------------------------------------------------------------------
__global__ __launch_bounds__(TPB, 8) void main_kernel(
        const float* __restrict__ z, const float* __restrict__ ws,
        float* __restrict__ out, long long B) {
    const int tid = threadIdx.x;
    const long long j0 = ((long long)blockIdx.x * TPB + tid) * JPT;

    // ---- streaming loads first ----
    const f32x4 c1 = *(const f32x4*)(z + 1 * B + j0);
    const f32x4 c2 = *(const f32x4*)(z + 2 * B + j0);
    const f32x4 c3 = *(const f32x4*)(z + 3 * B + j0);
    const f32x4 c4 = *(const f32x4*)(z + 4 * B + j0);
    const f32x4 c5 = *(const f32x4*)(z + 5 * B + j0);
    f32x4 q[6];
    #pragma unroll
    for (int v = 0; v < 6; ++v)
        q[v] = *(const f32x4*)(z + j0 * 6 + v * 4);

    // ---- Mc: uniform-address, read-only -> s_load broadcast ----
    float M[4][7];
    #pragma unroll
    for (int m = 0; m < 4; ++m) {
        #pragma unroll
        for (int k = 0; k < 7; ++k) M[m][k] = ws[m * 8 + k];
    }

    const float g1 = TAU * ALPHA3;
    const float g2 = TAU * ALPHA1;
    const float g3 = 1.f - TAU * ALPHA2 - TAU * ALPHA3;
    const float g4 = -TAU * ALPHA1;
    const float g5 = TAU * ALPHA2 - 1.f;
    const float invA1 = -0.25f;                 // 1/(-TAU), exact
    const float invA2 = -1.f / (TAU * ALPHA3);

    float zz[24];
    #pragma unroll
    for (int v = 0; v < 6; ++v) {
        zz[v * 4 + 0] = q[v].x; zz[v * 4 + 1] = q[v].y;
        zz[v * 4 + 2] = q[v].z; zz[v * 4 + 3] = q[v].w;
    }

    f32x4 o;
    #pragma unroll
    for (int r = 0; r < 4; ++r) {
        float u[4];
        #pragma unroll
        for (int m = 0; m < 4; ++m) {
            float s = M[m][6];
            #pragma unroll
            for (int k = 0; k < 6; ++k)
                s = fmaf(M[m][k], zz[r * 6 + k], s);
            u[m] = s;
        }
        const float x1 = c1[r], x2 = c2[r], x3 = c3[r];
        const float x4 = c4[r], x5 = c5[r];

        const float fx2 = x1 - x3;
        const float fx3 = ALPHA3 * x1 + ALPHA1 * x2 - ALPHA2 * x3;
        const float fx4 = x3 - x5;
        const float fx5 = ALPHA3 * x3 + ALPHA1 * x4 - ALPHA2 * x5;

        const float eta1 = x2 + S_STAR - TAU * (x3 - x1);
        const float bb1  = (fx2 - TAU * fx3) + u[1] * eta1;

        const float eta2a = x4 + S_STAR - TAU * (x5 - x3);
        const float eta2b = g1 * x1 + g2 * x2 + g3 * x3 + g4 * x4 + g5 * x5;
        const float d3ufX = g2 * fx2 + g3 * fx3 + g4 * fx4 + g5 * fx5;
        const float bb2   = d3ufX + u[2] * eta2a + u[3] * eta2b;

        const float lb = fmaxf(bb1 * invA1, bb2 * invA2);
        const float xu = 2.f * u[0];
        o[r] = fminf(fmaxf(xu, lb), 1e30f);
    }
    *(f32x4*)(out + j0) = o;
}

extern "C" void kernel_launch(void* const* d_in, const int* in_sizes, int n_in,
                              void* d_out, int out_size, void* d_ws, size_t ws_size,
                              hipStream_t stream) {
    const float* z  = (const float*)d_in[0];
    // d_in[1] = tilde_vh (unused by the reference output)
    const float* W1 = (const float*)d_in[2];
    const float* b1 = (const float*)d_in[3];
    const float* W2 = (const float*)d_in[4];
    const float* b2 = (const float*)d_in[5];
    const float* W3 = (const float*)d_in[6];
    const float* b3 = (const float*)d_in[7];
    float* out = (float*)d_out;
    float* ws  = (float*)d_ws;

    const long long B = (long long)in_sizes[0] / 6;   // 1048576

    setup_kernel<<<1, TPB, 0, stream>>>(W1, b1, W2, b2, W3, b3, ws);

    const int blocks = (int)(B / JPB);                // 1024
    main_kernel<<<blocks, TPB, 0, stream>>>(z, ws, out, B);
}

// Round 12
// 88.201 us; speedup vs baseline: 1.8484x; 1.1021x over previous
//
#include <hip/hip_runtime.h>

#define ALPHA1 1.2566f
#define ALPHA2 1.5f
#define ALPHA3 0.9f
#define S_STAR 20.0f
#define TAU    4.0f

constexpr int TPB = 256;
constexpr int JPT = 2;             // j's per thread (2 beats 4: TLP > per-thread ILP here, R10)
constexpr int JPB = TPB * JPT;     // 512 j's per block

typedef float f32x4 __attribute__((ext_vector_type(4)));
typedef float f32x2 __attribute__((ext_vector_type(2)));

// ---------------------------------------------------------------------------
// Setup (1 block): fold the purely-linear MLP into Mc[4][8] in d_ws.
// Split-launch publication: the kernel boundary's flush makes ws visible to
// all XCDs (device-scope flag through dirty-poisoned ws lines is NOT
// reliable -- measured round 8: every block timed out and fell back).
// ---------------------------------------------------------------------------
__global__ __launch_bounds__(TPB) void setup_kernel(
        const float* __restrict__ W1, const float* __restrict__ b1,
        const float* __restrict__ W2, const float* __restrict__ b2,
        const float* __restrict__ W3, const float* __restrict__ b3,
        float* __restrict__ ws) {
    __shared__ float T[100][8];
    __shared__ float W3s[400];
    __shared__ float b3s[4];
    const int tid = threadIdx.x;

    if (tid >= 128 && tid < 228) {
        const int i = tid - 128;
        *(f32x4*)(&W3s[i * 4]) = *(const f32x4*)(W3 + i * 4);
    } else if (tid >= 228 && tid < 232) {
        b3s[tid - 228] = b3[tid - 228];
    }

    if (tid < 100) {
        float acc[7] = {0.f, 0.f, 0.f, 0.f, 0.f, 0.f, 0.f};
        acc[6] = b2[tid];
        const float2* wrow = (const float2*)(W2 + tid * 50);
        #pragma unroll 5
        for (int hh = 0; hh < 25; ++hh) {
            const float2 w = wrow[hh];
            const int h = 2 * hh;
            // W1/b1 indices thread-uniform -> s_load broadcasts
            #pragma unroll
            for (int k = 0; k < 6; ++k)
                acc[k] = fmaf(w.y, W1[(h + 1) * 6 + k],
                          fmaf(w.x, W1[h * 6 + k], acc[k]));
            acc[6] = fmaf(w.y, b1[h + 1], fmaf(w.x, b1[h], acc[6]));
        }
        #pragma unroll
        for (int k = 0; k < 7; ++k) T[tid][k] = acc[k];
    }
    __syncthreads();

    if (tid < 28) {
        const int m = tid / 7, k = tid % 7;
        float s = (k == 6) ? b3s[m] : 0.f;
        #pragma unroll 10
        for (int i = 0; i < 100; ++i)
            s = fmaf(W3s[m * 100 + i], T[i][k], s);
        ws[m * 8 + k] = s;
    }
    if (tid >= 28 && tid < 32) ws[(tid - 28) * 8 + 7] = 0.f;
}

// ---------------------------------------------------------------------------
// Main: barrier-free, LDS-free streaming, 2 j's per thread, 2048 blocks
// (8 blocks/CU — max TLP; JPT=4/1024 blocks measured slower, R10).
// Mc via uniform-address s_load broadcasts (L2-hot after first wave).
// ---------------------------------------------------------------------------
__global__ __launch_bounds__(TPB, 8) void main_kernel(
        const float* __restrict__ z, const float* __restrict__ ws,
        float* __restrict__ out, long long B) {
    const int tid = threadIdx.x;
    const long long j0 = ((long long)blockIdx.x * TPB + tid) * JPT;

    // ---- streaming loads first ----
    const f32x2 c1 = *(const f32x2*)(z + 1 * B + j0);
    const f32x2 c2 = *(const f32x2*)(z + 2 * B + j0);
    const f32x2 c3 = *(const f32x2*)(z + 3 * B + j0);
    const f32x2 c4 = *(const f32x2*)(z + 4 * B + j0);
    const f32x2 c5 = *(const f32x2*)(z + 5 * B + j0);
    const f32x4 r0 = *(const f32x4*)(z + j0 * 6);
    const f32x4 r1 = *(const f32x4*)(z + j0 * 6 + 4);
    const f32x4 r2 = *(const f32x4*)(z + j0 * 6 + 8);

    // ---- Mc: uniform-address, read-only -> s_load broadcast ----
    float M[4][7];
    #pragma unroll
    for (int m = 0; m < 4; ++m) {
        #pragma unroll
        for (int k = 0; k < 7; ++k) M[m][k] = ws[m * 8 + k];
    }

    const float g1 = TAU * ALPHA3;
    const float g2 = TAU * ALPHA1;
    const float g3 = 1.f - TAU * ALPHA2 - TAU * ALPHA3;
    const float g4 = -TAU * ALPHA1;
    const float g5 = TAU * ALPHA2 - 1.f;
    const float invA1 = -0.25f;                 // 1/(-TAU), exact
    const float invA2 = -1.f / (TAU * ALPHA3);

    const float zz[12] = {r0.x, r0.y, r0.z, r0.w,
                          r1.x, r1.y, r1.z, r1.w,
                          r2.x, r2.y, r2.z, r2.w};

    f32x2 o;
    #pragma unroll
    for (int r = 0; r < 2; ++r) {
        float u[4];
        #pragma unroll
        for (int m = 0; m < 4; ++m) {
            float s = M[m][6];
            #pragma unroll
            for (int k = 0; k < 6; ++k)
                s = fmaf(M[m][k], zz[r * 6 + k], s);
            u[m] = s;
        }
        const float x1 = r ? c1.y : c1.x;
        const float x2 = r ? c2.y : c2.x;
        const float x3 = r ? c3.y : c3.x;
        const float x4 = r ? c4.y : c4.x;
        const float x5 = r ? c5.y : c5.x;

        const float fx2 = x1 - x3;
        const float fx3 = ALPHA3 * x1 + ALPHA1 * x2 - ALPHA2 * x3;
        const float fx4 = x3 - x5;
        const float fx5 = ALPHA3 * x3 + ALPHA1 * x4 - ALPHA2 * x5;

        const float eta1 = x2 + S_STAR - TAU * (x3 - x1);
        const float bb1  = (fx2 - TAU * fx3) + u[1] * eta1;

        const float eta2a = x4 + S_STAR - TAU * (x5 - x3);
        const float eta2b = g1 * x1 + g2 * x2 + g3 * x3 + g4 * x4 + g5 * x5;
        const float d3ufX = g2 * fx2 + g3 * fx3 + g4 * fx4 + g5 * fx5;
        const float bb2   = d3ufX + u[2] * eta2a + u[3] * eta2b;

        const float lb = fmaxf(bb1 * invA1, bb2 * invA2);
        const float xu = 2.f * u[0];
        o[r] = fminf(fmaxf(xu, lb), 1e30f);
    }
    *(f32x2*)(out + j0) = o;
}

extern "C" void kernel_launch(void* const* d_in, const int* in_sizes, int n_in,
                              void* d_out, int out_size, void* d_ws, size_t ws_size,
                              hipStream_t stream) {
    const float* z  = (const float*)d_in[0];
    // d_in[1] = tilde_vh (unused by the reference output)
    const float* W1 = (const float*)d_in[2];
    const float* b1 = (const float*)d_in[3];
    const float* W2 = (const float*)d_in[4];
    const float* b2 = (const float*)d_in[5];
    const float* W3 = (const float*)d_in[6];
    const float* b3 = (const float*)d_in[7];
    float* out = (float*)d_out;
    float* ws  = (float*)d_ws;

    const long long B = (long long)in_sizes[0] / 6;   // 1048576

    setup_kernel<<<1, TPB, 0, stream>>>(W1, b1, W2, b2, W3, b3, ws);

    const int blocks = (int)(B / JPB);                // 2048
    main_kernel<<<blocks, TPB, 0, stream>>>(z, ws, out, B);
}